// Round 1
// baseline (220.465 us; speedup 1.0000x reference)
//
#include <hip/hip_runtime.h>
#include <hip/hip_fp16.h>

// SelfAttention: B=8, C=64, N=64*64=4096, d_head=8.
// o[b,c,m] = gamma * sum_n h[b,c,n] * softmax_n(f[:,n].g[:,m]) + x[b,c,m]
// Strategy: proj kernel (fp32 VALU) -> fp16 fT[N][8], gT[N][8], h[64][N] in ws;
// flash-style fused attention with MFMA: scores 16x16x32_f16 (K padded 8->32),
// PV 16x16x16f16 whose B-frag layout == score D-frag layout (no LDS transpose).

typedef _Float16 half8_t __attribute__((ext_vector_type(8)));
typedef _Float16 half4_t __attribute__((ext_vector_type(4)));
typedef float float4_t __attribute__((ext_vector_type(4)));

#define NTOK 4096

// ---------------- projection: f = Wq x + bq, g = Wk x + bk, h = Wv x + bv ----
__global__ __launch_bounds__(320) void proj_kernel(
    const float* __restrict__ x,
    const float* __restrict__ Wq, const float* __restrict__ bq,
    const float* __restrict__ Wk, const float* __restrict__ bk,
    const float* __restrict__ Wv, const float* __restrict__ bv,
    __half* __restrict__ fT, __half* __restrict__ gT, __half* __restrict__ hM)
{
    __shared__ float xl[64][128];   // 32 KB
    __shared__ float Wl[80][64];    // 20 KB (rows 0..7 Wq, 8..15 Wk, 16..79 Wv)
    __shared__ float bl[80];
    const int t  = threadIdx.x;
    const int b  = blockIdx.y;
    const int n0 = blockIdx.x * 128;

    for (int i = t; i < 80 * 64; i += 320) {
        int o = i >> 6, c = i & 63;
        float w = (o < 8) ? Wq[o * 64 + c] : (o < 16) ? Wk[(o - 8) * 64 + c]
                                                      : Wv[(o - 16) * 64 + c];
        Wl[o][c] = w;
    }
    if (t < 80) bl[t] = (t < 8) ? bq[t] : (t < 16) ? bk[t - 8] : bv[t - 16];
    for (int i = t; i < 64 * 128; i += 320) {
        int c = i >> 7, j = i & 127;
        xl[c][j] = x[((b * 64 + c) << 12) + n0 + j];
    }
    __syncthreads();

    const int og = t >> 3;          // 0..39 -> output rows 2*og, 2*og+1
    const int colg = t & 7;         // 8 groups of 16 columns
    const int o0 = og * 2, o1 = o0 + 1;
    float a0[16], a1[16];
#pragma unroll
    for (int i = 0; i < 16; i++) { a0[i] = 0.f; a1[i] = 0.f; }
    for (int c = 0; c < 64; c++) {
        float w0 = Wl[o0][c], w1 = Wl[o1][c];
#pragma unroll
        for (int i = 0; i < 16; i++) {
            float xv = xl[c][colg * 16 + i];
            a0[i] += w0 * xv;
            a1[i] += w1 * xv;
        }
    }
    const int n = n0 + colg * 16;
    float* accs[2] = {a0, a1};
    int    os[2]   = {o0, o1};
#pragma unroll
    for (int s = 0; s < 2; s++) {
        int o = os[s];
        float bias = bl[o];
        float* a = accs[s];
        if (o < 8) {
#pragma unroll
            for (int i = 0; i < 16; i++)
                fT[(size_t)((b << 12) + n + i) * 8 + o] = __float2half(a[i] + bias);
        } else if (o < 16) {
#pragma unroll
            for (int i = 0; i < 16; i++)
                gT[(size_t)((b << 12) + n + i) * 8 + (o - 8)] = __float2half(a[i] + bias);
        } else {
            int c = o - 16;
            __half* dst = hM + (size_t)((b * 64 + c) << 12) + n;
#pragma unroll
            for (int i = 0; i < 16; i += 2)
                *(__half2*)(dst + i) =
                    __halves2half2(__float2half(a[i] + bias), __float2half(a[i + 1] + bias));
        }
    }
}

// ---------------- fused flash attention ------------------------------------
// block = 256 thr = 4 waves; wave w owns 16 columns (m = blk*64 + w*16 + lane&15)
// K-loop over 32 tiles of 128 keys. LDS holds only the h tile (padded).
#define PR 136   // padded row stride in halfs (272 B = 17*16: 16B aligned, odd*4 bank rotation)

__global__ __launch_bounds__(256) void attn_kernel(
    const __half* __restrict__ fT, const __half* __restrict__ gT,
    const __half* __restrict__ hM, const float* __restrict__ x,
    const float* __restrict__ gammap, float* __restrict__ out)
{
    __shared__ _Float16 hl[64 * PR];   // 17.4 KB
    const int tid  = threadIdx.x;
    const int w    = tid >> 6;
    const int lane = tid & 63;
    const int q    = lane >> 4;
    const int ml   = lane & 15;
    const int b    = blockIdx.y;
    const int col  = blockIdx.x * 64 + w * 16 + ml;

    // g B-frag: lanes q==0 hold g[d=0..7][col]; others zero (K padded to 32)
    half8_t gfrag = {};
    if (q == 0) gfrag = *(const half8_t*)(gT + (size_t)((b << 12) + col) * 8);

    float4_t acc[4];
#pragma unroll
    for (int cg = 0; cg < 4; cg++) acc[cg] = (float4_t){0.f, 0.f, 0.f, 0.f};
    float run_m = -INFINITY, run_l = 0.f;

    const __half* hbase = hM + ((size_t)(b * 64) << 12);
    const __half* fbb   = fT + (size_t)(b << 12) * 8;

    for (int kt = 0; kt < 32; ++kt) {
        const int n0 = kt * 128;
        __syncthreads();   // previous tile's reads complete
        // stage h tile [64 ch][128 keys] fp16 into padded LDS
        for (int k = tid; k < 1024; k += 256) {
            int c = k >> 4, cx = k & 15;
            uint4 v = *(const uint4*)(hbase + ((size_t)c << 12) + n0 + cx * 8);
            *(uint4*)(hl + c * PR + cx * 8) = v;
        }
        __syncthreads();

        // ---- scores: S[n][col] for n in tile (8 MFMA, K=32 zero-padded) ----
        float4_t st[8];
        const __half* fbase = fbb + (size_t)n0 * 8;
#pragma unroll
        for (int t8 = 0; t8 < 8; t8++) {
            half8_t af = {};
            if (q == 0) af = *(const half8_t*)(fbase + (size_t)(t8 * 16 + ml) * 8);
            st[t8] = __builtin_amdgcn_mfma_f32_16x16x32_f16(
                af, gfrag, (float4_t){0.f, 0.f, 0.f, 0.f}, 0, 0, 0);
        }

        // ---- online softmax over the 128 keys of this tile ----
        float tm = -INFINITY;
#pragma unroll
        for (int t8 = 0; t8 < 8; t8++)
#pragma unroll
            for (int r = 0; r < 4; r++) tm = fmaxf(tm, st[t8][r]);
        tm = fmaxf(tm, __shfl_xor(tm, 16, 64));
        tm = fmaxf(tm, __shfl_xor(tm, 32, 64));
        const float nm    = fmaxf(run_m, tm);
        const float alpha = __expf(run_m - nm);
        run_m = nm;
        float ls = 0.f;
#pragma unroll
        for (int t8 = 0; t8 < 8; t8++)
#pragma unroll
            for (int r = 0; r < 4; r++) {
                float p = __expf(st[t8][r] - nm);
                st[t8][r] = p;
                ls += p;
            }
        ls += __shfl_xor(ls, 16, 64);
        ls += __shfl_xor(ls, 32, 64);
        run_l = run_l * alpha + ls;
#pragma unroll
        for (int cg = 0; cg < 4; cg++)
#pragma unroll
            for (int r = 0; r < 4; r++) acc[cg][r] *= alpha;

        // ---- PV: K=16 MFMA; B-frag == score D-frag (in-lane fp32->fp16) ----
#pragma unroll
        for (int t8 = 0; t8 < 8; t8++) {
            half4_t pf = {(_Float16)st[t8][0], (_Float16)st[t8][1],
                          (_Float16)st[t8][2], (_Float16)st[t8][3]};
#pragma unroll
            for (int cg = 0; cg < 4; cg++) {
                half4_t ah = *(const half4_t*)(hl + (cg * 16 + ml) * PR + t8 * 16 + q * 4);
                acc[cg] = __builtin_amdgcn_mfma_f32_16x16x16f16(ah, pf, acc[cg], 0, 0, 0);
            }
        }
    }

    // ---- epilogue: o = gamma * acc / l + x ----
    const float scale = gammap[0] / run_l;
#pragma unroll
    for (int cg = 0; cg < 4; cg++)
#pragma unroll
        for (int r = 0; r < 4; r++) {
            int ch = cg * 16 + q * 4 + r;
            size_t idx = ((size_t)(b * 64 + ch) << 12) + col;
            out[idx] = scale * acc[cg][r] + x[idx];
        }
}

extern "C" void kernel_launch(void* const* d_in, const int* in_sizes, int n_in,
                              void* d_out, int out_size, void* d_ws, size_t ws_size,
                              hipStream_t stream) {
    const float* x     = (const float*)d_in[0];
    const float* Wq    = (const float*)d_in[1];
    const float* bq    = (const float*)d_in[2];
    const float* Wk    = (const float*)d_in[3];
    const float* bk    = (const float*)d_in[4];
    const float* Wv    = (const float*)d_in[5];
    const float* bv    = (const float*)d_in[6];
    const float* gamma = (const float*)d_in[7];
    float* out = (float*)d_out;

    // workspace layout (fp16): fT [8][4096][8], gT [8][4096][8], h [8][64][4096]
    __half* fT = (__half*)d_ws;
    __half* gT = fT + (size_t)8 * NTOK * 8;
    __half* hM = gT + (size_t)8 * NTOK * 8;

    proj_kernel<<<dim3(32, 8), 320, 0, stream>>>(x, Wq, bq, Wk, bk, Wv, bv, fT, gT, hM);
    attn_kernel<<<dim3(64, 8), 256, 0, stream>>>(fT, gT, hM, x, gamma, out);
}